// Round 6
// baseline (229.065 us; speedup 1.0000x reference)
//
#include <hip/hip_runtime.h>

typedef unsigned short ushort_t;
typedef __attribute__((ext_vector_type(8))) __bf16 bf16x8;
typedef __attribute__((ext_vector_type(4))) float floatx4;

__device__ __forceinline__ ushort_t f2bf(float f) {
    unsigned int u = __builtin_bit_cast(unsigned int, f);
    u = (u + 0x7fffu + ((u >> 16) & 1u)) >> 16;
    return (ushort_t)u;
}

__device__ __forceinline__ void async16(const ushort_t* g, ushort_t* l) {
    __builtin_amdgcn_global_load_lds(
        (const __attribute__((address_space(1))) unsigned int*)g,
        (__attribute__((address_space(3))) unsigned int*)l,
        16 /*bytes*/, 0 /*offset*/, 0 /*aux*/);
}

// XCD-chunked bijective blockIdx swizzle (nwg % 8 == 0).
__device__ __forceinline__ int xcd_swz(int bid, int cpx) {
    return (bid & 7) * cpx + (bid >> 3);
}

// ===========================================================================
// FREE-RUN triple-buffer core (the R5-verified winner): ONE vmcnt + ONE
// s_barrier per K-tile; no intra-tile barriers. Stage(t+2) -> buf[(t+2)%3],
// whose last read was in tile t-1 and all waves passed barrier-t after those
// reads -> disjoint. vmcnt(6) leaves the 6 loads of tile t+1 in flight
// (2 tiles ≈ 5000 cyc of slack >> 900 cyc HBM latency; never drains to 0 in
// steady state). Within a tile waves free-run (compiler lgkmcnt does
// ds_read->MFMA ordering); wave skew overlaps LDS reads with MFMA.
// Read swizzle: 16B-slot = (kk*4+quad)^(row&7), staged via pre-swizzled
// global source + linear LDS dest.
// ---------------------------------------------------------------------------
// fr_bn256: 128x256 / BK=64 / 8-wave / triple-buffer (144 KB).
// Buffer layout (ushorts, SL=24576): A[128][64] @0 ; B[256][64] @8192.
// Wave (wm 0..1)x(wn 0..3), per-wave C = 64x64 = acc[4][4]; B fc-major.
// ---------------------------------------------------------------------------
template <int MODE>   // 0 steady (stage t+2, vmcnt6) | 1 penult (vmcnt6) | 2 last (vmcnt0)
__device__ __forceinline__ void frbn_tile(
    const ushort_t* __restrict__ sb, ushort_t* __restrict__ dst,
    const ushort_t* __restrict__ gA, const ushort_t* __restrict__ gB,
    int lda, int ldb, long koff,
    int rb0, int rb1, int ab, int bb,
    floatx4 (&acc)[4][4]) {

    if constexpr (MODE == 2) asm volatile("s_waitcnt vmcnt(0)");
    else                     asm volatile("s_waitcnt vmcnt(6)");
    __builtin_amdgcn_s_barrier();

    if constexpr (MODE == 0) {
        async16(gA + koff,                   dst);
        async16(gA + (long)64 * lda + koff,  dst + 4096);
        async16(gB + koff,                   dst + 8192);
        async16(gB + (long)64 * ldb + koff,  dst + 12288);
        async16(gB + (long)128 * ldb + koff, dst + 16384);
        async16(gB + (long)192 * ldb + koff, dst + 20480);
    }

    bf16x8 aR[4][2], bKc[2][2], bCc[2][2];
    // phase 1: fc 0-1
#pragma unroll
    for (int fr = 0; fr < 4; fr++) {
        aR[fr][0] = *(const bf16x8*)&sb[ab + fr * 1024 + rb0];
        aR[fr][1] = *(const bf16x8*)&sb[ab + fr * 1024 + rb1];
    }
#pragma unroll
    for (int fc = 0; fc < 2; fc++) {
        bKc[fc][0] = *(const bf16x8*)&sb[bb + fc * 4096 + rb0];
        bKc[fc][1] = *(const bf16x8*)&sb[bb + fc * 4096 + rb1];
    }
    __builtin_amdgcn_s_setprio(1);
#pragma unroll
    for (int fr = 0; fr < 4; fr++)
#pragma unroll
        for (int fc = 0; fc < 2; fc++) {
            acc[fr][fc] = __builtin_amdgcn_mfma_f32_16x16x32_bf16(
                aR[fr][0], bKc[fc][0], acc[fr][fc], 0, 0, 0);
            acc[fr][fc] = __builtin_amdgcn_mfma_f32_16x16x32_bf16(
                aR[fr][1], bKc[fc][1], acc[fr][fc], 0, 0, 0);
        }
    __builtin_amdgcn_s_setprio(0);

    // phase 2: fc 2-3
#pragma unroll
    for (int fc = 0; fc < 2; fc++) {
        bCc[fc][0] = *(const bf16x8*)&sb[bb + (fc + 2) * 4096 + rb0];
        bCc[fc][1] = *(const bf16x8*)&sb[bb + (fc + 2) * 4096 + rb1];
    }
    __builtin_amdgcn_s_setprio(1);
#pragma unroll
    for (int fr = 0; fr < 4; fr++)
#pragma unroll
        for (int fc = 0; fc < 2; fc++) {
            acc[fr][fc + 2] = __builtin_amdgcn_mfma_f32_16x16x32_bf16(
                aR[fr][0], bCc[fc][0], acc[fr][fc + 2], 0, 0, 0);
            acc[fr][fc + 2] = __builtin_amdgcn_mfma_f32_16x16x32_bf16(
                aR[fr][1], bCc[fc][1], acc[fr][fc + 2], 0, 0, 0);
        }
    __builtin_amdgcn_s_setprio(0);
}

__device__ __forceinline__ void gemm_frbn(
    const ushort_t* __restrict__ A, int lda,
    const ushort_t* __restrict__ B, int ldb,
    int K, int tile_m, int tile_n,
    ushort_t* buf,                      // 73728 ushorts = 144 KB
    floatx4 (&acc)[4][4]) {

    const int tid  = threadIdx.x;
    const int lane = tid & 63;
    const int wave = tid >> 6;
    const int wm   = wave >> 2;
    const int wn   = wave & 3;
    const int quad = lane >> 4;
    const int l16  = lane & 15;

#pragma unroll
    for (int i = 0; i < 4; i++)
#pragma unroll
        for (int j = 0; j < 4; j++) acc[i][j] = (floatx4){0.f, 0.f, 0.f, 0.f};

    const int srow = tid >> 3;
    const int scg  = (tid & 7) ^ (srow & 7);
    const ushort_t* gA = A + (long)(tile_m + srow) * lda + scg * 8;
    const ushort_t* gB = B + (long)(tile_n + srow) * ldb + scg * 8;
    ushort_t* const ld = buf + tid * 8;

    const int rb0 = l16 * 64 + (((quad)     ^ (l16 & 7)) << 3);
    const int rb1 = l16 * 64 + (((quad + 4) ^ (l16 & 7)) << 3);
    const int ab = wm * 4096;                 // A row = wm*64 + fr*16 + l16
    const int bb = 8192 + wn * 1024;          // B row = fc*64 + wn*16 + l16

    const int nt = K >> 6;

    // prologue: t0 -> buf0, t1 -> buf1
    async16(gA,                        ld);
    async16(gA + (long)64 * lda,       ld + 4096);
    async16(gB,                        ld + 8192);
    async16(gB + (long)64 * ldb,       ld + 12288);
    async16(gB + (long)128 * ldb,      ld + 16384);
    async16(gB + (long)192 * ldb,      ld + 20480);
    async16(gA + 64,                   ld + 24576);
    async16(gA + (long)64 * lda + 64,  ld + 24576 + 4096);
    async16(gB + 64,                   ld + 24576 + 8192);
    async16(gB + (long)64 * ldb + 64,  ld + 24576 + 12288);
    async16(gB + (long)128 * ldb + 64, ld + 24576 + 16384);
    async16(gB + (long)192 * ldb + 64, ld + 24576 + 20480);

    int cur = 0;
    int t = 0;
#pragma unroll 1
    for (; t < nt - 2; ++t) {
        const int nx = (cur == 0) ? 2 : cur - 1;   // (cur+2)%3
        frbn_tile<0>(buf + cur * 24576, ld + nx * 24576,
                     gA, gB, lda, ldb, (long)(t + 2) * 64,
                     rb0, rb1, ab, bb, acc);
        cur = (cur == 2) ? 0 : cur + 1;
    }
    frbn_tile<1>(buf + cur * 24576, ld, gA, gB, lda, ldb, 0,
                 rb0, rb1, ab, bb, acc);
    cur = (cur == 2) ? 0 : cur + 1;
    frbn_tile<2>(buf + cur * 24576, ld, gA, gB, lda, ldb, 0,
                 rb0, rb1, ab, bb, acc);
}

// ---------------------------------------------------------------------------
// prep: fp32->bf16 for x & W_v, zero lsum, transpose+cast Wq/Wk -> WqT/WkT
// ---------------------------------------------------------------------------
__global__ void prep_kernel(const float* __restrict__ x,
                            const float* __restrict__ wq,
                            const float* __restrict__ wk,
                            const float* __restrict__ wv,
                            ushort_t* __restrict__ xb,
                            ushort_t* __restrict__ wvb,
                            ushort_t* __restrict__ wqT,
                            ushort_t* __restrict__ wkT,
                            float* __restrict__ lsum) {
    const int bx = blockIdx.x;
    const int t = threadIdx.x;
    if (bx < 9216) {
        const float* src;
        ushort_t* dst;
        long g;
        if (bx < 8192) { src = x;  dst = xb;  g = ((long)bx * 256 + t) * 4; }
        else           { src = wv; dst = wvb; g = ((long)(bx - 8192) * 256 + t) * 4; }
        float4 v = *(const float4*)(src + g);
        ushort4 o;
        o.x = f2bf(v.x); o.y = f2bf(v.y); o.z = f2bf(v.z); o.w = f2bf(v.w);
        *(ushort4*)(dst + g) = o;
        return;
    }
    if (bx < 9224) {
        int idx = (bx - 9216) * 256 + t;  // [0,2048)
        ((float4*)lsum)[idx] = (float4){0.f, 0.f, 0.f, 0.f};
        return;
    }
    const int tt = bx - 9224;           // [0,512)
    const float* src = (tt >= 256) ? wk : wq;
    ushort_t* dst = (tt >= 256) ? wkT : wqT;
    const int id = tt & 255;
    const int h0 = (id >> 4) * 64, d0 = (id & 15) * 64;
    __shared__ ushort_t tile[64 * 80];
    {
        int i = t >> 2, cg = (t & 3) << 4;
        const float4* p = (const float4*)(src + (long)(h0 + i) * 1024 + d0 + cg);
#pragma unroll
        for (int k = 0; k < 4; k++) {
            float4 v = p[k];
            ushort_t* q = &tile[i * 80 + cg + k * 4];
            q[0] = f2bf(v.x); q[1] = f2bf(v.y); q[2] = f2bf(v.z); q[3] = f2bf(v.w);
        }
    }
    __syncthreads();
    {
        int j = t >> 2, ig = (t & 3) << 4;
        ushort_t tmp[16];
#pragma unroll
        for (int k = 0; k < 16; k++) tmp[k] = tile[(ig + k) * 80 + j];
        ushort_t* o = dst + (long)(d0 + j) * 1024 + h0 + ig;
        *(uint4*)o = ((uint4*)tmp)[0];
        *(uint4*)(o + 8) = ((uint4*)tmp)[1];
    }
}

// ---------------------------------------------------------------------------
// gv: blocks [0,32) -> G (8m x 4n of 128x256) ; [32,288) -> V^T (8m x 32n).
// free-run t3 core, 288 blocks (swizzle cpx=36, bijective).
// ---------------------------------------------------------------------------
__global__ __launch_bounds__(512, 2) void gv_kernel(
    const ushort_t* __restrict__ wkT, const ushort_t* __restrict__ wqT,
    const ushort_t* __restrict__ wvb, const ushort_t* __restrict__ xb,
    ushort_t* __restrict__ Gb, ushort_t* __restrict__ VTb) {

    __shared__ __align__(16) ushort_t buf[73728];   // 144 KB

    const int lin = xcd_swz(blockIdx.x, 36);
    const ushort_t *A, *B;
    ushort_t* C;
    int ldc, tile_m, tile_n;
    if (lin < 32) {          // G[e][d] = sum_h WkT[e][h] WqT[d][h]
        A = wkT; B = wqT; C = Gb; ldc = 1024;
        tile_m = (lin >> 2) * 128;          // 8 m-tiles
        tile_n = (lin & 3) * 256;           // 4 n-tiles
    } else {                 // VT[h][s] = sum_d Wv[h][d] x[s][d]
        int id = lin - 32;                  // [0,256)
        A = wvb; B = xb; C = VTb; ldc = 8192;
        tile_m = (id >> 5) * 128;           // 8 m-tiles
        tile_n = (id & 31) * 256;           // 32 n-tiles
    }

    floatx4 acc[4][4];
    gemm_frbn(A, 1024, B, 1024, 1024, tile_m, tile_n, buf, acc);

    const int lane = threadIdx.x & 63, wave = threadIdx.x >> 6;
    const int wm = wave >> 2, wn = wave & 3, quad = lane >> 4, l16 = lane & 15;
#pragma unroll
    for (int fr = 0; fr < 4; fr++)
#pragma unroll
        for (int r = 0; r < 4; r++) {
            int row = tile_m + wm * 64 + fr * 16 + quad * 4 + r;
#pragma unroll
            for (int fc = 0; fc < 4; fc++) {
                int col = tile_n + fc * 64 + wn * 16 + l16;
                C[(long)row * ldc + col] = f2bf(acc[fr][fc][r]);
            }
        }
}

// ---------------------------------------------------------------------------
// Y = x G^T  (M=8192, N=1024, K=1024; 128x256 tiles, 256 blocks = 1/CU)
// ---------------------------------------------------------------------------
__global__ __launch_bounds__(512, 2) void y_kernel(
    const ushort_t* __restrict__ xb,
    const ushort_t* __restrict__ Gb,
    ushort_t* __restrict__ Yb) {

    __shared__ __align__(16) ushort_t buf[73728];   // 144 KB
    const int lin = xcd_swz(blockIdx.x, 32);        // 256 blocks
    const int tile_m = (lin >> 2) * 128;            // 64 m-tiles
    const int tile_n = (lin & 3) * 256;             // 4 n-tiles (fastest)

    floatx4 acc[4][4];
    gemm_frbn(xb, 1024, Gb, 1024, 1024, tile_m, tile_n, buf, acc);

    const int lane = threadIdx.x & 63, wave = threadIdx.x >> 6;
    const int wm = wave >> 2, wn = wave & 3, quad = lane >> 4, l16 = lane & 15;
#pragma unroll
    for (int fr = 0; fr < 4; fr++)
#pragma unroll
        for (int r = 0; r < 4; r++) {
            int row = tile_m + wm * 64 + fr * 16 + quad * 4 + r;
#pragma unroll
            for (int fc = 0; fc < 4; fc++) {
                int col = tile_n + fc * 64 + wn * 16 + l16;
                Yb[(long)row * 1024 + col] = f2bf(acc[fr][fc][r]);
            }
        }
}

// ---------------------------------------------------------------------------
// P = exp(scale * Y x^T) per batch + fused row-sum atomics.
// NOW on the frbn t3 core: 128x256 tiles, per batch 16m x 8n = 128 blocks,
// 512 total = exactly 2 rounds at 1 block/CU. vmcnt(6), 2-tile prefetch.
// ---------------------------------------------------------------------------
__global__ __launch_bounds__(512, 2) void pexp_kernel(
    const ushort_t* __restrict__ Yb,
    const ushort_t* __restrict__ xb,
    ushort_t* __restrict__ Pb,
    float* __restrict__ lsum) {

    __shared__ __align__(16) ushort_t buf[73728];   // 144 KB

    const int lin = xcd_swz(blockIdx.x, 64);   // 512 blocks, bijective
    const int z = lin >> 7;                    // batch
    const int tile_m = ((lin >> 3) & 15) * 128; // 16 m-tiles
    const int tile_n = (lin & 7) * 256;         // 8 n-tiles (fastest)

    const ushort_t* A = Yb + (long)z * 2097152;
    const ushort_t* B = xb + (long)z * 2097152;
    ushort_t* C = Pb + (long)z * 4194304;
    float* l = lsum + z * 2048;

    floatx4 acc[4][4];
    gemm_frbn(A, 1024, B, 1024, 1024, tile_m, tile_n, buf, acc);

    const float scale = 0.022097086912079608f;  // 1/sqrt(2048)
    const int lane = threadIdx.x & 63, wave = threadIdx.x >> 6;
    const int wm = wave >> 2, wn = wave & 3, quad = lane >> 4, l16 = lane & 15;
#pragma unroll
    for (int fr = 0; fr < 4; fr++)
#pragma unroll
        for (int r = 0; r < 4; r++) {
            int row = tile_m + wm * 64 + fr * 16 + quad * 4 + r;
            float psum = 0.f;
#pragma unroll
            for (int fc = 0; fc < 4; fc++) {
                int col = tile_n + fc * 64 + wn * 16 + l16;
                float e = __expf(acc[fr][fc][r] * scale);
                C[(long)row * 2048 + col] = f2bf(e);
                psum += e;
            }
            psum += __shfl_xor(psum, 1, 64);
            psum += __shfl_xor(psum, 2, 64);
            psum += __shfl_xor(psum, 4, 64);
            psum += __shfl_xor(psum, 8, 64);
            if (l16 == 0) atomicAdd(&l[row], psum);
        }
}

// ---------------------------------------------------------------------------
// out = (P V) / l per batch  (128x256 tiles, K=2048, 256 blocks = 1/CU)
// ---------------------------------------------------------------------------
__global__ __launch_bounds__(512, 2) void out_kernel(
    const ushort_t* __restrict__ Pb,
    const ushort_t* __restrict__ VTb,
    float* __restrict__ out,
    const float* __restrict__ lsum) {

    __shared__ __align__(16) ushort_t buf[73728];   // 144 KB

    const int lin = xcd_swz(blockIdx.x, 32);   // 256 blocks
    const int z = lin >> 6;                    // batch
    const int tile_m = ((lin >> 2) & 15) * 128;// 16 m-tiles
    const int tile_n = (lin & 3) * 256;        // 4 n-tiles (fastest)

    const ushort_t* A = Pb + (long)z * 4194304;   // [2048][2048]
    const ushort_t* B = VTb + (long)z * 2048;     // ldb=8192, batch col slice
    float* C = out + (long)z * 2097152;
    const float* l = lsum + z * 2048;

    floatx4 acc[4][4];
    gemm_frbn(A, 2048, B, 8192, 2048, tile_m, tile_n, buf, acc);

    const int lane = threadIdx.x & 63, wave = threadIdx.x >> 6;
    const int wm = wave >> 2, wn = wave & 3, quad = lane >> 4, l16 = lane & 15;
#pragma unroll
    for (int fr = 0; fr < 4; fr++)
#pragma unroll
        for (int r = 0; r < 4; r++) {
            int row = tile_m + wm * 64 + fr * 16 + quad * 4 + r;
            float li = 1.0f / l[row];
#pragma unroll
            for (int fc = 0; fc < 4; fc++) {
                int col = tile_n + fc * 64 + wn * 16 + l16;
                C[(long)row * 1024 + col] = acc[fr][fc][r] * li;
            }
        }
}

// ---------------------------------------------------------------------------
extern "C" void kernel_launch(void* const* d_in, const int* in_sizes, int n_in,
                              void* d_out, int out_size, void* d_ws, size_t ws_size,
                              hipStream_t stream) {
    const float* x  = (const float*)d_in[0];
    const float* wq = (const float*)d_in[1];
    const float* wk = (const float*)d_in[2];
    const float* wv = (const float*)d_in[3];

    ushort_t* xb  = (ushort_t*)d_ws;          // [8192,1024] bf16
    ushort_t* wvb = xb  + 8388608;            // [1024,1024]
    ushort_t* wqT = wvb + 1048576;            // [1024,1024]
    ushort_t* wkT = wqT + 1048576;            // [1024,1024]
    ushort_t* Gb  = wkT + 1048576;            // [1024,1024]
    ushort_t* Yb  = Gb  + 1048576;            // [8192,1024]
    ushort_t* VTb = Yb  + 8388608;            // [1024,8192]
    ushort_t* Pb  = VTb + 8388608;            // [4][2048][2048]
    float*    lsum = (float*)(Pb + 16777216); // [4][2048]
    float*    out  = (float*)d_out;

    prep_kernel<<<9736, 256, 0, stream>>>(x, wq, wk, wv, xb, wvb, wqT, wkT, lsum);
    gv_kernel<<<288, 512, 0, stream>>>(wkT, wqT, wvb, xb, Gb, VTb);
    y_kernel<<<256, 512, 0, stream>>>(xb, Gb, Yb);
    pexp_kernel<<<512, 512, 0, stream>>>(Yb, xb, Pb, lsum);
    out_kernel<<<256, 512, 0, stream>>>(Pb, VTb, out, lsum);
}